// Round 1
// baseline (713.065 us; speedup 1.0000x reference)
//
#include <hip/hip_runtime.h>
#include <math.h>

#define EPS 1e-5f
// dims: n=8, C=512, t=8, h=32, w=32, K=8, S=4 (hb=wb=8), TS=2 (tb=4), TK=8
// group size for P/Q/TM over channels: C/8 = 64

// ---------------------------------------------------------------------------
// K1: conv1(1x1x1, 512->8) + BN1 + ReLU computed on the fly; block-local
// reductions produce rp (row max-pool), cp (col max-pool, atomicMax),
// tp partial sums (atomicAdd). o is never materialized.
// grid (hq=4, t=8, n=8), 256 threads: block covers rows hh in [hq*8,hq*8+8).
// Note hq == h-block index a, so rp needs no atomics.
// ---------------------------------------------------------------------------
__global__ __launch_bounds__(256) void k_conv1_pool(
    const float* __restrict__ x,  const float* __restrict__ w1,
    const float* __restrict__ b1, const float* __restrict__ g1,
    const float* __restrict__ bb1,const float* __restrict__ m1,
    const float* __restrict__ v1,
    float* __restrict__ rp, float* __restrict__ cp, float* __restrict__ tps)
{
    const int hq  = blockIdx.x;   // 0..3  (= h-block a)
    const int t   = blockIdx.y;   // 0..7
    const int nn  = blockIdx.z;   // 0..7
    const int tid = threadIdx.x;  // 0..255 = u*32 + ww

    __shared__ float o_s[8 * 256];
    __shared__ float red_max[8 * 32];
    __shared__ float red_sum[8 * 32];

    const float* xb = x + (size_t)nn * 512 * 8192 + t * 1024 + hq * 256 + tid;

    float acc[8];
#pragma unroll
    for (int k = 0; k < 8; k++) acc[k] = 0.f;

    for (int c = 0; c < 512; c += 8) {
#pragma unroll
        for (int cc = 0; cc < 8; cc++) {
            float xv = xb[(size_t)(c + cc) * 8192];
#pragma unroll
            for (int k = 0; k < 8; k++)
                acc[k] += w1[k * 512 + c + cc] * xv;  // uniform -> scalar loads
        }
    }
#pragma unroll
    for (int k = 0; k < 8; k++) {
        float sc  = g1[k] * rsqrtf(v1[k] + EPS);
        float val = (acc[k] + b1[k] - m1[k]) * sc + bb1[k];
        o_s[k * 256 + tid] = fmaxf(val, 0.f);
    }
    __syncthreads();

    // stage A: partial reduce over runs of 8 (fixed u, fixed b, v=0..7)
    {
        int k = tid >> 5;        // 0..7
        int j = tid & 31;        // j = u*4 + b
        const float* p = &o_s[k * 256 + j * 8];
        float mx = p[0], sm = p[0];
#pragma unroll
        for (int i = 1; i < 8; i++) { mx = fmaxf(mx, p[i]); sm += p[i]; }
        red_max[k * 32 + j] = mx;
        red_sum[k * 32 + j] = sm;
    }
    __syncthreads();

    if (tid < 32) {  // cp[n,k,t,b]: max over u (and v already folded)
        int k = tid >> 2, b = tid & 3;
        float mx = red_max[k * 32 + b];
#pragma unroll
        for (int u = 1; u < 8; u++) mx = fmaxf(mx, red_max[k * 32 + u * 4 + b]);
        // post-ReLU values >= 0: int-compare on float bits is order-preserving
        atomicMax((int*)&cp[((nn * 8 + k) * 8 + t) * 4 + b], __float_as_int(mx));
    }
    if (tid < 8) {   // rp[n,k,t,a=hq] exact; tp partial sum
        int k = tid;
        float mx = red_max[k * 32], sm = red_sum[k * 32];
#pragma unroll
        for (int j = 1; j < 32; j++) {
            mx = fmaxf(mx, red_max[k * 32 + j]);
            sm += red_sum[k * 32 + j];
        }
        rp[((nn * 8 + k) * 8 + t) * 4 + hq] = mx;
        atomicAdd(&tps[(nn * 8 + k) * 2 + (t >> 2)], sm);
    }
}

// ---------------------------------------------------------------------------
// K2: conv_p/conv_q/conv_t + softmaxes -> P[n,kc,t,a,b], Q[n,kc,t,a,b],
// TM[n,kk,a2,b2]. grid (n=8), 256 threads.
// ---------------------------------------------------------------------------
__global__ __launch_bounds__(256) void k_pqtm(
    const float* __restrict__ rp, const float* __restrict__ cp,
    const float* __restrict__ tps,
    const float* __restrict__ pw, const float* __restrict__ pb,
    const float* __restrict__ qw, const float* __restrict__ qb,
    const float* __restrict__ tw, const float* __restrict__ tbv,
    float* __restrict__ P, float* __restrict__ Q, float* __restrict__ TM)
{
    const int nn  = blockIdx.x;
    const int tid = threadIdx.x;
    __shared__ float rps[256], cps[256], tpss[16];
    rps[tid] = rp[nn * 256 + tid];
    cps[tid] = cp[nn * 256 + tid];
    if (tid < 16) tpss[tid] = tps[nn * 16 + tid] * (1.0f / 4096.0f);
    __syncthreads();

    // p: tid = k*32 + a*8 + t; softmax over b
    {
        int k = tid >> 5, a = (tid >> 3) & 3, t = tid & 7;
        float v[4];
#pragma unroll
        for (int b = 0; b < 4; b++) {
            int o = k * 16 + a * 4 + b;
            float s = pb[o];
#pragma unroll
            for (int c = 0; c < 8; c++)
#pragma unroll
                for (int i = 0; i < 4; i++)
                    s += pw[o * 32 + c * 4 + i] * rps[c * 32 + t * 4 + i];
            v[b] = s;
        }
        float mx = fmaxf(fmaxf(v[0], v[1]), fmaxf(v[2], v[3]));
        float e[4]; float sum = 0.f;
#pragma unroll
        for (int b = 0; b < 4; b++) { e[b] = expf(v[b] - mx); sum += e[b]; }
        float inv = 1.f / sum;
        int base = ((nn * 8 + k) * 8 + t) * 16 + a * 4;
#pragma unroll
        for (int b = 0; b < 4; b++) P[base + b] = e[b] * inv;
    }
    // q: tid = k*32 + b*8 + t; softmax over a
    {
        int k = tid >> 5, b = (tid >> 3) & 3, t = tid & 7;
        float v[4];
#pragma unroll
        for (int a = 0; a < 4; a++) {
            int o = k * 16 + a * 4 + b;
            float s = qb[o];
#pragma unroll
            for (int c = 0; c < 8; c++)
#pragma unroll
                for (int i = 0; i < 4; i++)
                    s += qw[o * 32 + c * 4 + i] * cps[c * 32 + t * 4 + i];
            v[a] = s;
        }
        float mx = fmaxf(fmaxf(v[0], v[1]), fmaxf(v[2], v[3]));
        float e[4]; float sum = 0.f;
#pragma unroll
        for (int a = 0; a < 4; a++) { e[a] = expf(v[a] - mx); sum += e[a]; }
        float inv = 1.f / sum;
        int base = ((nn * 8 + k) * 8 + t) * 16 + b;
#pragma unroll
        for (int a = 0; a < 4; a++) Q[base + a * 4] = e[a] * inv;
    }
    // tm: tid = kk*2 + a2 (<16); softmax over b2
    if (tid < 16) {
        int kk = tid >> 1, a2 = tid & 1;
        float v[2];
#pragma unroll
        for (int b2 = 0; b2 < 2; b2++) {
            int o = kk * 4 + a2 * 2 + b2;
            float s = tbv[o];
#pragma unroll
            for (int c = 0; c < 8; c++)
#pragma unroll
                for (int i = 0; i < 2; i++)
                    s += tw[o * 16 + c * 2 + i] * tpss[c * 2 + i];
            v[b2] = s;
        }
        float mx = fmaxf(v[0], v[1]);
        float e0 = expf(v[0] - mx), e1 = expf(v[1] - mx);
        float inv = 1.f / (e0 + e1);
        TM[nn * 32 + kk * 4 + a2 * 2 + 0] = e0 * inv;
        TM[nn * 32 + kk * 4 + a2 * 2 + 1] = e1 * inv;
    }
}

// ---------------------------------------------------------------------------
// K3a: block-linear mixing y3 = TM o (Q o (P o x)).
// grid (u2=4, c=512, n=8), 256 threads. Block processes t-planes u2 and u2+4,
// produces output planes tt=u2 and tt=u2+4. Thread's 4 positions are strided
// by 256 (one per h-block) so LDS access is <=2-way conflicted.
// ---------------------------------------------------------------------------
__global__ __launch_bounds__(256) void k_mix(
    const float* __restrict__ x, const float* __restrict__ P,
    const float* __restrict__ Q, const float* __restrict__ TM,
    float* __restrict__ y3)
{
    const int u2  = blockIdx.x;   // 0..3
    const int c   = blockIdx.y;   // 0..511
    const int nn  = blockIdx.z;   // 0..7
    const int tid = threadIdx.x;  // = u*32 + ww
    const int kc  = c >> 6;

    __shared__ float x0s[1024], x1s[1024], z0s[1024], z1s[1024];

    const size_t xb = ((size_t)(nn * 512 + c) * 8 + u2) * 1024;
    *(float4*)&x0s[tid * 4] = *(const float4*)&x[xb + tid * 4];
    *(float4*)&x1s[tid * 4] = *(const float4*)&x[xb + 4096 + tid * 4];

    const float* Pb0 = &P[((nn * 8 + kc) * 8 + u2) * 16];
    const float* Pb1 = Pb0 + 4 * 16;
    const float* Qb0 = &Q[((nn * 8 + kc) * 8 + u2) * 16];
    const float* Qb1 = Qb0 + 4 * 16;
    const float* TMb = &TM[nn * 32 + kc * 4];

    const int u = tid >> 5, ww = tid & 31;
    const int bw = ww >> 3, v = ww & 7;

    float P0[4][4], P1[4][4], Q0[4], Q1[4];
#pragma unroll
    for (int a = 0; a < 4; a++) {
#pragma unroll
        for (int b = 0; b < 4; b++) {
            P0[a][b] = Pb0[a * 4 + b];
            P1[a][b] = Pb1[a * 4 + b];
        }
        Q0[a] = Qb0[a * 4 + bw];
        Q1[a] = Qb1[a * 4 + bw];
    }
    const float tm00 = TMb[0], tm01 = TMb[1], tm10 = TMb[2], tm11 = TMb[3];
    __syncthreads();

    // h-mix: z[ah*8+u][ww] = sum_bh P[ah][bh] * x[bh*8+u][ww]
    float xv0[4], xv1[4];
#pragma unroll
    for (int bh = 0; bh < 4; bh++) {
        xv0[bh] = x0s[bh * 256 + tid];
        xv1[bh] = x1s[bh * 256 + tid];
    }
#pragma unroll
    for (int ah = 0; ah < 4; ah++) {
        float s0 = 0.f, s1 = 0.f;
#pragma unroll
        for (int bh = 0; bh < 4; bh++) {
            s0 += P0[ah][bh] * xv0[bh];
            s1 += P1[ah][bh] * xv1[bh];
        }
        z0s[ah * 256 + tid] = s0;
        z1s[ah * 256 + tid] = s1;
    }
    __syncthreads();

    // w-mix + temporal combine, direct store
    const size_t ob0 = xb;          // plane tt = u2
    const size_t ob1 = xb + 4096;   // plane tt = u2+4
#pragma unroll
    for (int kidx = 0; kidx < 4; kidx++) {
        int rb = kidx * 256 + u * 32 + v;
        float y20 = 0.f, y21 = 0.f;
#pragma unroll
        for (int aw = 0; aw < 4; aw++) {
            y20 += Q0[aw] * z0s[rb + aw * 8];
            y21 += Q1[aw] * z1s[rb + aw * 8];
        }
        int p = kidx * 256 + tid;
        y3[ob0 + p] = tm00 * y20 + tm01 * y21;
        y3[ob1 + p] = tm10 * y20 + tm11 * y21;
    }
}

// ---------------------------------------------------------------------------
// K3b: conv2 (512x512) + BN2 + ReLU as register-tiled fp32 GEMM.
// grid (pos tiles=64, co tiles=4, n=8), 256 threads; 128x128 block tile,
// 8x8 per-thread tile, K-chunks of 8 staged through LDS.
// ---------------------------------------------------------------------------
__global__ __launch_bounds__(256) void k_gemm2(
    const float* __restrict__ y3, const float* __restrict__ w2,
    const float* __restrict__ b2, const float* __restrict__ g2,
    const float* __restrict__ bb2,const float* __restrict__ m2,
    const float* __restrict__ v2, float* __restrict__ out)
{
    const int pt  = blockIdx.x;   // 0..63
    const int ct  = blockIdx.y;   // 0..3
    const int nn  = blockIdx.z;   // 0..7
    const int tid = threadIdx.x;
    const int p0  = pt * 128, co0 = ct * 128;

    __shared__ float ws_[8 * 128];
    __shared__ float ys_[8 * 128];

    float acc[8][8];
#pragma unroll
    for (int i = 0; i < 8; i++)
#pragma unroll
        for (int j = 0; j < 8; j++) acc[i][j] = 0.f;

    const int cw  = tid >> 4, pwi = tid & 15;
    const int lco = tid >> 1, lc4 = (tid & 1) * 4;   // w2 tile load
    const int yc  = tid >> 5, yp4 = (tid & 31) * 4;  // y3 tile load
    const size_t ybase = (size_t)nn * 512 * 8192 + p0;

    for (int c0 = 0; c0 < 512; c0 += 8) {
        float4 wv = *(const float4*)&w2[(size_t)(co0 + lco) * 512 + c0 + lc4];
        ws_[(lc4 + 0) * 128 + lco] = wv.x;
        ws_[(lc4 + 1) * 128 + lco] = wv.y;
        ws_[(lc4 + 2) * 128 + lco] = wv.z;
        ws_[(lc4 + 3) * 128 + lco] = wv.w;
        *(float4*)&ys_[yc * 128 + yp4] =
            *(const float4*)&y3[ybase + (size_t)(c0 + yc) * 8192 + yp4];
        __syncthreads();
#pragma unroll
        for (int cc = 0; cc < 8; cc++) {
            float4 a0 = *(float4*)&ws_[cc * 128 + cw * 8];
            float4 a1 = *(float4*)&ws_[cc * 128 + cw * 8 + 4];
            float4 b0 = *(float4*)&ys_[cc * 128 + pwi * 8];
            float4 b1 = *(float4*)&ys_[cc * 128 + pwi * 8 + 4];
            float av[8] = {a0.x, a0.y, a0.z, a0.w, a1.x, a1.y, a1.z, a1.w};
            float bv[8] = {b0.x, b0.y, b0.z, b0.w, b1.x, b1.y, b1.z, b1.w};
#pragma unroll
            for (int i = 0; i < 8; i++)
#pragma unroll
                for (int j = 0; j < 8; j++) acc[i][j] += av[i] * bv[j];
        }
        __syncthreads();
    }
    // epilogue: bias + BN2 + ReLU
#pragma unroll
    for (int i = 0; i < 8; i++) {
        int co = co0 + cw * 8 + i;
        float sc   = g2[co] * rsqrtf(v2[co] + EPS);
        float base = (b2[co] - m2[co]) * sc + bb2[co];
        float4 o0, o1;
        o0.x = fmaxf(acc[i][0] * sc + base, 0.f);
        o0.y = fmaxf(acc[i][1] * sc + base, 0.f);
        o0.z = fmaxf(acc[i][2] * sc + base, 0.f);
        o0.w = fmaxf(acc[i][3] * sc + base, 0.f);
        o1.x = fmaxf(acc[i][4] * sc + base, 0.f);
        o1.y = fmaxf(acc[i][5] * sc + base, 0.f);
        o1.z = fmaxf(acc[i][6] * sc + base, 0.f);
        o1.w = fmaxf(acc[i][7] * sc + base, 0.f);
        size_t ob = (size_t)(nn * 512 + co) * 8192 + p0 + pwi * 8;
        *(float4*)&out[ob]     = o0;
        *(float4*)&out[ob + 4] = o1;
    }
}

// ---------------------------------------------------------------------------
extern "C" void kernel_launch(void* const* d_in, const int* in_sizes, int n_in,
                              void* d_out, int out_size, void* d_ws, size_t ws_size,
                              hipStream_t stream) {
    const float* x   = (const float*)d_in[0];
    const float* w1  = (const float*)d_in[1];
    const float* b1  = (const float*)d_in[2];
    const float* g1  = (const float*)d_in[3];
    const float* bb1 = (const float*)d_in[4];
    const float* m1  = (const float*)d_in[5];
    const float* v1  = (const float*)d_in[6];
    const float* pw  = (const float*)d_in[7];
    const float* pb  = (const float*)d_in[8];
    const float* qw  = (const float*)d_in[9];
    const float* qb  = (const float*)d_in[10];
    const float* tw  = (const float*)d_in[11];
    const float* tbv = (const float*)d_in[12];
    const float* w2  = (const float*)d_in[13];
    const float* b2  = (const float*)d_in[14];
    const float* g2  = (const float*)d_in[15];
    const float* bb2 = (const float*)d_in[16];
    const float* m2  = (const float*)d_in[17];
    const float* v2  = (const float*)d_in[18];

    float* ws  = (float*)d_ws;
    float* rp  = ws;            // 2048
    float* cp  = ws + 2048;     // 2048
    float* tps = ws + 4096;     // 128
    float* P   = ws + 8192;     // 8192
    float* Q   = ws + 16384;    // 8192
    float* TM  = ws + 24576;    // 256
    float* y3  = ws + 32768;    // 33554432 (128 MiB)

    // zero the atomic-reduction region (ws is poisoned 0xAA by harness)
    hipMemsetAsync(ws, 0, 4224 * sizeof(float), stream);

    k_conv1_pool<<<dim3(4, 8, 8), 256, 0, stream>>>(x, w1, b1, g1, bb1, m1, v1,
                                                    rp, cp, tps);
    k_pqtm<<<dim3(8), 256, 0, stream>>>(rp, cp, tps, pw, pb, qw, qb, tw, tbv,
                                        P, Q, TM);
    k_mix<<<dim3(4, 512, 8), 256, 0, stream>>>(x, P, Q, TM, y3);
    k_gemm2<<<dim3(64, 4, 8), 256, 0, stream>>>(y3, w2, b2, g2, bb2, m2, v2,
                                                (float*)d_out);
}

// Round 2
// 409.215 us; speedup vs baseline: 1.7425x; 1.7425x over previous
//
#include <hip/hip_runtime.h>
#include <math.h>

#define EPS 1e-5f
// dims: n=8, C=512, t=8, h=32, w=32, K=8, S=4 (hb=wb=8), TS=2 (tb=4), TK=8

typedef __bf16 bf16x8 __attribute__((ext_vector_type(8)));
typedef float f32x4 __attribute__((ext_vector_type(4)));

__device__ static inline unsigned short f2bf(float f) {
    unsigned u = __float_as_uint(f);
    unsigned r = (u + 0x7fffu + ((u >> 16) & 1u)) >> 16;  // RNE
    return (unsigned short)r;
}

__device__ static inline void load_lds16(const void* g, void* l) {
    __builtin_amdgcn_global_load_lds(
        (const __attribute__((address_space(1))) unsigned int*)g,
        (__attribute__((address_space(3))) unsigned int*)l, 16, 0, 0);
}

// ---------------------------------------------------------------------------
// K0: w2 fp32 -> bf16
// ---------------------------------------------------------------------------
__global__ __launch_bounds__(256) void k_w2cast(const float* __restrict__ w2,
                                                unsigned short* __restrict__ w2bf) {
    int i = (blockIdx.x * 256 + threadIdx.x) * 4;
    float4 v = *(const float4*)&w2[i];
    ushort4 o;
    o.x = f2bf(v.x); o.y = f2bf(v.y); o.z = f2bf(v.z); o.w = f2bf(v.w);
    *(ushort4*)&w2bf[i] = o;
}

// ---------------------------------------------------------------------------
// K1: conv1(512->8) + BN1 + ReLU on the fly; pools rp/cp/tp. 1024 threads,
// 4-way c-split (ch = tid>>8) for 16 waves/CU latency hiding; LDS combine.
// grid (hq=4, t=8, n=8).
// ---------------------------------------------------------------------------
__global__ __launch_bounds__(1024) void k_conv1_pool(
    const float* __restrict__ x,  const float* __restrict__ w1,
    const float* __restrict__ b1, const float* __restrict__ g1,
    const float* __restrict__ bb1,const float* __restrict__ m1,
    const float* __restrict__ v1,
    float* __restrict__ rp, float* __restrict__ cp, float* __restrict__ tps)
{
    const int hq  = blockIdx.x;   // 0..3 (= h-block a)
    const int t   = blockIdx.y;   // 0..7
    const int nn  = blockIdx.z;   // 0..7
    const int tid = threadIdx.x;  // 0..1023
    const int ch  = tid >> 8;     // c-quarter 0..3
    const int pos = tid & 255;    // u*32 + ww

    __shared__ float part[4][8][256];   // 32 KB
    __shared__ float o_s[8 * 256];      //  8 KB
    __shared__ float red_max[8 * 32];
    __shared__ float red_sum[8 * 32];

    const float* xb = x + (size_t)nn * 512 * 8192 + (size_t)ch * 128 * 8192
                        + t * 1024 + hq * 256 + pos;
    const float* wb = w1 + ch * 128;

    float acc[8];
#pragma unroll
    for (int k = 0; k < 8; k++) acc[k] = 0.f;

    for (int c = 0; c < 128; c += 8) {
#pragma unroll
        for (int cc = 0; cc < 8; cc++) {
            float xv = xb[(size_t)(c + cc) * 8192];
#pragma unroll
            for (int k = 0; k < 8; k++)
                acc[k] += wb[k * 512 + c + cc] * xv;  // wave-uniform -> scalar
        }
    }
#pragma unroll
    for (int k = 0; k < 8; k++) part[ch][k][pos] = acc[k];
    __syncthreads();

    if (tid < 256) {
#pragma unroll
        for (int k = 0; k < 8; k++) {
            float s = part[0][k][tid] + part[1][k][tid] +
                      part[2][k][tid] + part[3][k][tid];
            float sc  = g1[k] * rsqrtf(v1[k] + EPS);
            float val = (s + b1[k] - m1[k]) * sc + bb1[k];
            o_s[k * 256 + tid] = fmaxf(val, 0.f);
        }
    }
    __syncthreads();

    if (tid < 256) {  // partial reduce over v runs of 8 (fixed u, fixed b)
        int k = tid >> 5, j = tid & 31;  // j = u*4 + b
        const float* p = &o_s[k * 256 + j * 8];
        float mx = p[0], sm = p[0];
#pragma unroll
        for (int i = 1; i < 8; i++) { mx = fmaxf(mx, p[i]); sm += p[i]; }
        red_max[k * 32 + j] = mx;
        red_sum[k * 32 + j] = sm;
    }
    __syncthreads();

    if (tid < 32) {  // cp[n,k,t,b]: max over u
        int k = tid >> 2, b = tid & 3;
        float mx = red_max[k * 32 + b];
#pragma unroll
        for (int u = 1; u < 8; u++) mx = fmaxf(mx, red_max[k * 32 + u * 4 + b]);
        atomicMax((int*)&cp[((nn * 8 + k) * 8 + t) * 4 + b], __float_as_int(mx));
    }
    if (tid < 8) {   // rp[n,k,t,a=hq] exact; tp partial sum
        int k = tid;
        float mx = red_max[k * 32], sm = red_sum[k * 32];
#pragma unroll
        for (int j = 1; j < 32; j++) {
            mx = fmaxf(mx, red_max[k * 32 + j]);
            sm += red_sum[k * 32 + j];
        }
        rp[((nn * 8 + k) * 8 + t) * 4 + hq] = mx;
        atomicAdd(&tps[(nn * 8 + k) * 2 + (t >> 2)], sm);
    }
}

// ---------------------------------------------------------------------------
// K2: conv_p/conv_q/conv_t + softmaxes -> P, Q, TM. grid (n=8), 256 threads.
// ---------------------------------------------------------------------------
__global__ __launch_bounds__(256) void k_pqtm(
    const float* __restrict__ rp, const float* __restrict__ cp,
    const float* __restrict__ tps,
    const float* __restrict__ pw, const float* __restrict__ pb,
    const float* __restrict__ qw, const float* __restrict__ qb,
    const float* __restrict__ tw, const float* __restrict__ tbv,
    float* __restrict__ P, float* __restrict__ Q, float* __restrict__ TM)
{
    const int nn  = blockIdx.x;
    const int tid = threadIdx.x;
    __shared__ float rps[256], cps[256], tpss[16];
    rps[tid] = rp[nn * 256 + tid];
    cps[tid] = cp[nn * 256 + tid];
    if (tid < 16) tpss[tid] = tps[nn * 16 + tid] * (1.0f / 4096.0f);
    __syncthreads();

    {   // p: tid = k*32 + a*8 + t; softmax over b
        int k = tid >> 5, a = (tid >> 3) & 3, t = tid & 7;
        float v[4];
#pragma unroll
        for (int b = 0; b < 4; b++) {
            int o = k * 16 + a * 4 + b;
            float s = pb[o];
#pragma unroll
            for (int c = 0; c < 8; c++)
#pragma unroll
                for (int i = 0; i < 4; i++)
                    s += pw[o * 32 + c * 4 + i] * rps[c * 32 + t * 4 + i];
            v[b] = s;
        }
        float mx = fmaxf(fmaxf(v[0], v[1]), fmaxf(v[2], v[3]));
        float e[4]; float sum = 0.f;
#pragma unroll
        for (int b = 0; b < 4; b++) { e[b] = expf(v[b] - mx); sum += e[b]; }
        float inv = 1.f / sum;
        int base = ((nn * 8 + k) * 8 + t) * 16 + a * 4;
#pragma unroll
        for (int b = 0; b < 4; b++) P[base + b] = e[b] * inv;
    }
    {   // q: tid = k*32 + b*8 + t; softmax over a
        int k = tid >> 5, b = (tid >> 3) & 3, t = tid & 7;
        float v[4];
#pragma unroll
        for (int a = 0; a < 4; a++) {
            int o = k * 16 + a * 4 + b;
            float s = qb[o];
#pragma unroll
            for (int c = 0; c < 8; c++)
#pragma unroll
                for (int i = 0; i < 4; i++)
                    s += qw[o * 32 + c * 4 + i] * cps[c * 32 + t * 4 + i];
            v[a] = s;
        }
        float mx = fmaxf(fmaxf(v[0], v[1]), fmaxf(v[2], v[3]));
        float e[4]; float sum = 0.f;
#pragma unroll
        for (int a = 0; a < 4; a++) { e[a] = expf(v[a] - mx); sum += e[a]; }
        float inv = 1.f / sum;
        int base = ((nn * 8 + k) * 8 + t) * 16 + b;
#pragma unroll
        for (int a = 0; a < 4; a++) Q[base + a * 4] = e[a] * inv;
    }
    if (tid < 16) {  // tm: tid = kk*2 + a2; softmax over b2
        int kk = tid >> 1, a2 = tid & 1;
        float v[2];
#pragma unroll
        for (int b2 = 0; b2 < 2; b2++) {
            int o = kk * 4 + a2 * 2 + b2;
            float s = tbv[o];
#pragma unroll
            for (int c = 0; c < 8; c++)
#pragma unroll
                for (int i = 0; i < 2; i++)
                    s += tw[o * 16 + c * 2 + i] * tpss[c * 2 + i];
            v[b2] = s;
        }
        float mx = fmaxf(v[0], v[1]);
        float e0 = expf(v[0] - mx), e1 = expf(v[1] - mx);
        float inv = 1.f / (e0 + e1);
        TM[nn * 32 + kk * 4 + a2 * 2 + 0] = e0 * inv;
        TM[nn * 32 + kk * 4 + a2 * 2 + 1] = e1 * inv;
    }
}

// ---------------------------------------------------------------------------
// K3a: block-linear mixing y3 = TM o (Q o (P o x)), bf16 output.
// grid (u2=4, c=512, n=8), 256 threads.
// ---------------------------------------------------------------------------
__global__ __launch_bounds__(256) void k_mix(
    const float* __restrict__ x, const float* __restrict__ P,
    const float* __restrict__ Q, const float* __restrict__ TM,
    unsigned short* __restrict__ y3bf)
{
    const int u2  = blockIdx.x;   // 0..3
    const int c   = blockIdx.y;   // 0..511
    const int nn  = blockIdx.z;   // 0..7
    const int tid = threadIdx.x;  // = u*32 + ww
    const int kc  = c >> 6;

    __shared__ float x0s[1024], x1s[1024], z0s[1024], z1s[1024];

    const size_t xb = ((size_t)(nn * 512 + c) * 8 + u2) * 1024;
    *(float4*)&x0s[tid * 4] = *(const float4*)&x[xb + tid * 4];
    *(float4*)&x1s[tid * 4] = *(const float4*)&x[xb + 4096 + tid * 4];

    const float* Pb0 = &P[((nn * 8 + kc) * 8 + u2) * 16];
    const float* Pb1 = Pb0 + 4 * 16;
    const float* Qb0 = &Q[((nn * 8 + kc) * 8 + u2) * 16];
    const float* Qb1 = Qb0 + 4 * 16;
    const float* TMb = &TM[nn * 32 + kc * 4];

    const int u = tid >> 5, ww = tid & 31;
    const int bw = ww >> 3, v = ww & 7;

    float P0[4][4], P1[4][4], Q0[4], Q1[4];
#pragma unroll
    for (int a = 0; a < 4; a++) {
#pragma unroll
        for (int b = 0; b < 4; b++) {
            P0[a][b] = Pb0[a * 4 + b];
            P1[a][b] = Pb1[a * 4 + b];
        }
        Q0[a] = Qb0[a * 4 + bw];
        Q1[a] = Qb1[a * 4 + bw];
    }
    const float tm00 = TMb[0], tm01 = TMb[1], tm10 = TMb[2], tm11 = TMb[3];
    __syncthreads();

    float xv0[4], xv1[4];
#pragma unroll
    for (int bh = 0; bh < 4; bh++) {
        xv0[bh] = x0s[bh * 256 + tid];
        xv1[bh] = x1s[bh * 256 + tid];
    }
#pragma unroll
    for (int ah = 0; ah < 4; ah++) {
        float s0 = 0.f, s1 = 0.f;
#pragma unroll
        for (int bh = 0; bh < 4; bh++) {
            s0 += P0[ah][bh] * xv0[bh];
            s1 += P1[ah][bh] * xv1[bh];
        }
        z0s[ah * 256 + tid] = s0;
        z1s[ah * 256 + tid] = s1;
    }
    __syncthreads();

    const size_t ob0 = xb;          // plane tt = u2
    const size_t ob1 = xb + 4096;   // plane tt = u2+4
#pragma unroll
    for (int kidx = 0; kidx < 4; kidx++) {
        int rb = kidx * 256 + u * 32 + v;
        float y20 = 0.f, y21 = 0.f;
#pragma unroll
        for (int aw = 0; aw < 4; aw++) {
            y20 += Q0[aw] * z0s[rb + aw * 8];
            y21 += Q1[aw] * z1s[rb + aw * 8];
        }
        int p = kidx * 256 + tid;
        y3bf[ob0 + p] = f2bf(tm00 * y20 + tm01 * y21);
        y3bf[ob1 + p] = f2bf(tm10 * y20 + tm11 * y21);
    }
}

// ---------------------------------------------------------------------------
// K3b: conv2 (512x512) + BN2 + ReLU, bf16 MFMA GEMM.
// Block tile 128(co) x 128(p), BK=64, 4 waves each computing 64x64 via 4x4
// 16x16x32 frags. B staged [c][p] via global_load_lds (B-frag reads are
// k-strided u16 — structural 4-way quad conflict, accepted this round).
// A staged via VGPR -> padded LDS (pitch 72) -> b128 frag reads (conflict-free).
// ---------------------------------------------------------------------------
__global__ __launch_bounds__(256) void k_gemm2(
    const unsigned short* __restrict__ y3bf,
    const unsigned short* __restrict__ w2bf,
    const float* __restrict__ b2, const float* __restrict__ g2,
    const float* __restrict__ bb2,const float* __restrict__ m2,
    const float* __restrict__ v2, float* __restrict__ out)
{
    const int ct  = blockIdx.x;   // 0..3  co-tile (innermost: shares y3 tile)
    const int pt  = blockIdx.y;   // 0..63 p-tile
    const int nn  = blockIdx.z;   // 0..7
    const int tid = threadIdx.x;
    const int co0 = ct * 128, p0 = pt * 128;

    __shared__ unsigned short Bs[64 * 128];  // 16 KB, [c][p] pitch 128
    __shared__ unsigned short As[128 * 72];  // 18 KB, [co][c] pitch 72 (pad)
    __shared__ float sc_s[128], ba_s[128];

    if (tid < 128) {
        int co = co0 + tid;
        float sc = g2[co] * rsqrtf(v2[co] + EPS);
        sc_s[tid] = sc;
        ba_s[tid] = (b2[co] - m2[co]) * sc + bb2[co];
    }

    const int lane = tid & 63, wv = tid >> 6;
    const int wr = wv >> 1, wc = wv & 1;       // wave 64x64 sub-tile
    const int ln15 = lane & 15, quad = lane >> 4;

    f32x4 acc[4][4];
#pragma unroll
    for (int i = 0; i < 4; i++)
#pragma unroll
        for (int j = 0; j < 4; j++) acc[i][j] = (f32x4){0.f, 0.f, 0.f, 0.f};

    const size_t ybase = (size_t)nn * 512 * 8192 + p0;
    const int aco = tid >> 1, aseg = tid & 1;
    const unsigned short* ag = w2bf + (size_t)(co0 + aco) * 512 + aseg * 32;

    for (int c0 = 0; c0 < 512; c0 += 64) {
        // B tile: async DMA, 4 rows (1 KB) per wave-issue, 4 issues per wave
#pragma unroll
        for (int it = 0; it < 4; it++) {
            int rbase = wv * 16 + it * 4;
            const unsigned short* gsrc =
                y3bf + ybase + (size_t)(c0 + rbase + quad) * 8192 + ln15 * 8;
            load_lds16(gsrc, &Bs[rbase * 128]);
        }
        // A tile: thread covers 32 c of one co row
        uint4 av4[4];
#pragma unroll
        for (int j = 0; j < 4; j++)
            av4[j] = *(const uint4*)(ag + c0 + j * 8);
#pragma unroll
        for (int j = 0; j < 4; j++)
            *(uint4*)&As[aco * 72 + aseg * 32 + j * 8] = av4[j];
        __syncthreads();

#pragma unroll
        for (int ks = 0; ks < 2; ks++) {
            bf16x8 a[4], b[4];
#pragma unroll
            for (int mi = 0; mi < 4; mi++)
                a[mi] = *(const bf16x8*)&As[(wr * 64 + mi * 16 + ln15) * 72 +
                                            ks * 32 + quad * 8];
#pragma unroll
            for (int pi = 0; pi < 4; pi++) {
                union { unsigned short u[8]; bf16x8 v; } bu;
                const unsigned short* bp =
                    &Bs[(ks * 32 + quad * 8) * 128 + wc * 64 + pi * 16 + ln15];
#pragma unroll
                for (int j = 0; j < 8; j++) bu.u[j] = bp[j * 128];
                b[pi] = bu.v;
            }
#pragma unroll
            for (int mi = 0; mi < 4; mi++)
#pragma unroll
                for (int pi = 0; pi < 4; pi++)
                    acc[mi][pi] = __builtin_amdgcn_mfma_f32_16x16x32_bf16(
                        a[mi], b[pi], acc[mi][pi], 0, 0, 0);
        }
        __syncthreads();
    }

    // epilogue: BN2 + ReLU. D layout: col(p)=lane&15, row(co)=quad*4+reg.
#pragma unroll
    for (int mi = 0; mi < 4; mi++) {
        int lco = wr * 64 + mi * 16 + quad * 4;
#pragma unroll
        for (int pi = 0; pi < 4; pi++) {
            int p = p0 + wc * 64 + pi * 16 + ln15;
#pragma unroll
            for (int r = 0; r < 4; r++) {
                float vv = acc[mi][pi][r] * sc_s[lco + r] + ba_s[lco + r];
                out[((size_t)nn * 512 + co0 + lco + r) * 8192 + p] =
                    fmaxf(vv, 0.f);
            }
        }
    }
}

// ---------------------------------------------------------------------------
extern "C" void kernel_launch(void* const* d_in, const int* in_sizes, int n_in,
                              void* d_out, int out_size, void* d_ws, size_t ws_size,
                              hipStream_t stream) {
    const float* x   = (const float*)d_in[0];
    const float* w1  = (const float*)d_in[1];
    const float* b1  = (const float*)d_in[2];
    const float* g1  = (const float*)d_in[3];
    const float* bb1 = (const float*)d_in[4];
    const float* m1  = (const float*)d_in[5];
    const float* v1  = (const float*)d_in[6];
    const float* pw  = (const float*)d_in[7];
    const float* pb  = (const float*)d_in[8];
    const float* qw  = (const float*)d_in[9];
    const float* qb  = (const float*)d_in[10];
    const float* tw  = (const float*)d_in[11];
    const float* tbv = (const float*)d_in[12];
    const float* w2  = (const float*)d_in[13];
    const float* b2  = (const float*)d_in[14];
    const float* g2  = (const float*)d_in[15];
    const float* bb2 = (const float*)d_in[16];
    const float* m2  = (const float*)d_in[17];
    const float* v2  = (const float*)d_in[18];

    float* ws  = (float*)d_ws;
    float* rp  = ws;            // 2048 floats
    float* cp  = ws + 2048;     // 2048
    float* tps = ws + 4096;     // 128
    float* P   = ws + 8192;     // 8192
    float* Q   = ws + 16384;    // 8192
    float* TM  = ws + 24576;    // 256
    unsigned short* w2bf = (unsigned short*)(ws + 32768);   // 262144 ushorts
    unsigned short* y3bf = (unsigned short*)(ws + 163840);  // 33554432 ushorts

    // zero the atomic-reduction region (ws is poisoned 0xAA by harness)
    hipMemsetAsync(ws, 0, 4224 * sizeof(float), stream);

    k_w2cast<<<dim3(256), 256, 0, stream>>>(w2, w2bf);
    k_conv1_pool<<<dim3(4, 8, 8), 1024, 0, stream>>>(x, w1, b1, g1, bb1, m1, v1,
                                                     rp, cp, tps);
    k_pqtm<<<dim3(8), 256, 0, stream>>>(rp, cp, tps, pw, pb, qw, qb, tw, tbv,
                                        P, Q, TM);
    k_mix<<<dim3(4, 512, 8), 256, 0, stream>>>(x, P, Q, TM, y3bf);
    k_gemm2<<<dim3(4, 64, 8), 256, 0, stream>>>(y3bf, w2bf, b2, g2, bb2, m2, v2,
                                                (float*)d_out);
}

// Round 3
// 365.601 us; speedup vs baseline: 1.9504x; 1.1193x over previous
//
#include <hip/hip_runtime.h>
#include <math.h>

#define EPS 1e-5f
// dims: n=8, C=512, t=8, h=32, w=32, K=8, S=4 (hb=wb=8), TS=2 (tb=4), TK=8

typedef __bf16 bf16x8 __attribute__((ext_vector_type(8)));
typedef float f32x4 __attribute__((ext_vector_type(4)));

__device__ static inline unsigned short f2bf(float f) {
    unsigned u = __float_as_uint(f);
    unsigned r = (u + 0x7fffu + ((u >> 16) & 1u)) >> 16;  // RNE
    return (unsigned short)r;
}

__device__ static inline void load_lds16(const void* g, void* l) {
    __builtin_amdgcn_global_load_lds(
        (const __attribute__((address_space(1))) unsigned int*)g,
        (__attribute__((address_space(3))) unsigned int*)l, 16, 0, 0);
}

// ---------------------------------------------------------------------------
// K0: w2 fp32 -> bf16
// ---------------------------------------------------------------------------
__global__ __launch_bounds__(256) void k_w2cast(const float* __restrict__ w2,
                                                unsigned short* __restrict__ w2bf) {
    int i = (blockIdx.x * 256 + threadIdx.x) * 4;
    float4 v = *(const float4*)&w2[i];
    ushort4 o;
    o.x = f2bf(v.x); o.y = f2bf(v.y); o.z = f2bf(v.z); o.w = f2bf(v.w);
    *(ushort4*)&w2bf[i] = o;
}

// ---------------------------------------------------------------------------
// K1: conv1(512->8)+BN1+ReLU on the fly; pools rp/cp/tp.
// grid (a=4, t=8, n=8), 512 threads = 8 waves. Wave wv owns channels
// [wv*64, wv*64+64) -> weights are wave-uniform (s_load). Lane owns float4
// of 4 consecutive positions in the 256-pos (a,t) tile -> 16B coalesced
// loads, 8 in flight. LDS combine across waves, shuffle-reduced pools.
// ---------------------------------------------------------------------------
__global__ __launch_bounds__(512) void k_conv1_pool(
    const float* __restrict__ x,  const float* __restrict__ w1,
    const float* __restrict__ b1, const float* __restrict__ g1,
    const float* __restrict__ bb1,const float* __restrict__ m1,
    const float* __restrict__ v1,
    float* __restrict__ rp, float* __restrict__ cp, float* __restrict__ tps)
{
    const int a   = blockIdx.x;   // 0..3 (h-block)
    const int t   = blockIdx.y;   // 0..7
    const int nn  = blockIdx.z;   // 0..7
    const int tid = threadIdx.x;  // 0..511
    const int wv  = tid >> 6;     // wave = c-group
    const int lane= tid & 63;

    __shared__ float part[8 * 8 * 256];  // [wv][k][pos] 64 KB

    const int cbase = __builtin_amdgcn_readfirstlane(wv) * 64;
    const float* xb = x + (size_t)nn * 512 * 8192 + (size_t)cbase * 8192
                        + t * 1024 + a * 256 + lane * 4;
    const float* wb = w1 + cbase;

    f32x4 acc[8];
#pragma unroll
    for (int k = 0; k < 8; k++) acc[k] = (f32x4){0.f, 0.f, 0.f, 0.f};

    for (int c = 0; c < 64; c += 8) {
        float4 xv[8];
#pragma unroll
        for (int cc = 0; cc < 8; cc++)
            xv[cc] = *(const float4*)(xb + (size_t)(c + cc) * 8192);
#pragma unroll
        for (int cc = 0; cc < 8; cc++) {
#pragma unroll
            for (int k = 0; k < 8; k++) {
                float wt = wb[k * 512 + c + cc];  // wave-uniform -> s_load
                acc[k][0] += wt * xv[cc].x;
                acc[k][1] += wt * xv[cc].y;
                acc[k][2] += wt * xv[cc].z;
                acc[k][3] += wt * xv[cc].w;
            }
        }
    }
#pragma unroll
    for (int k = 0; k < 8; k++)
        *(f32x4*)&part[(wv * 8 + k) * 256 + lane * 4] = acc[k];
    __syncthreads();

    // combine: thread = (k = tid>>6, lane): o for 4 consecutive positions
    {
        const int k = tid >> 6;
        f32x4 s = (f32x4){0.f, 0.f, 0.f, 0.f};
#pragma unroll
        for (int g = 0; g < 8; g++) {
            f32x4 p = *(const f32x4*)&part[(g * 8 + k) * 256 + lane * 4];
            s[0] += p[0]; s[1] += p[1]; s[2] += p[2]; s[3] += p[3];
        }
        const float sc = g1[k] * rsqrtf(v1[k] + EPS);
        const float ba = (b1[k] - m1[k]) * sc + bb1[k];
        float o0 = fmaxf(s[0] * sc + ba, 0.f);
        float o1 = fmaxf(s[1] * sc + ba, 0.f);
        float o2 = fmaxf(s[2] * sc + ba, 0.f);
        float o3 = fmaxf(s[3] * sc + ba, 0.f);

        float m4 = fmaxf(fmaxf(o0, o1), fmaxf(o2, o3));
        float s4 = o0 + o1 + o2 + o3;

        // rp[n,k,t,a]: max over all 256 pos (exact within block)
        float mr = m4;
#pragma unroll
        for (int m = 32; m >= 1; m >>= 1) mr = fmaxf(mr, __shfl_xor(mr, m, 64));
        if (lane == 0) rp[((nn * 8 + k) * 8 + t) * 4 + a] = mr;

        // cp[n,k,t,b]: b = bits 1..2 of lane; reduce over lane bits {0,3,4,5}
        float mc = m4;
        mc = fmaxf(mc, __shfl_xor(mc, 1, 64));
        mc = fmaxf(mc, __shfl_xor(mc, 8, 64));
        mc = fmaxf(mc, __shfl_xor(mc, 16, 64));
        mc = fmaxf(mc, __shfl_xor(mc, 32, 64));
        if ((lane & 0x39) == 0)  // lanes 0,2,4,6
            atomicMax((int*)&cp[((nn * 8 + k) * 8 + t) * 4 + (lane >> 1)],
                      __float_as_int(mc));

        // tp partial sum
        float ss = s4;
#pragma unroll
        for (int m = 32; m >= 1; m >>= 1) ss += __shfl_xor(ss, m, 64);
        if (lane == 0) atomicAdd(&tps[(nn * 8 + k) * 2 + (t >> 2)], ss);
    }
}

// ---------------------------------------------------------------------------
// K2: conv_p/conv_q/conv_t + softmaxes -> P, Q, TM. grid (n=8), 256 threads.
// ---------------------------------------------------------------------------
__global__ __launch_bounds__(256) void k_pqtm(
    const float* __restrict__ rp, const float* __restrict__ cp,
    const float* __restrict__ tps,
    const float* __restrict__ pw, const float* __restrict__ pb,
    const float* __restrict__ qw, const float* __restrict__ qb,
    const float* __restrict__ tw, const float* __restrict__ tbv,
    float* __restrict__ P, float* __restrict__ Q, float* __restrict__ TM)
{
    const int nn  = blockIdx.x;
    const int tid = threadIdx.x;
    __shared__ float rps[256], cps[256], tpss[16];
    rps[tid] = rp[nn * 256 + tid];
    cps[tid] = cp[nn * 256 + tid];
    if (tid < 16) tpss[tid] = tps[nn * 16 + tid] * (1.0f / 4096.0f);
    __syncthreads();

    {   // p: tid = k*32 + a*8 + t; softmax over b
        int k = tid >> 5, a = (tid >> 3) & 3, t = tid & 7;
        float v[4];
#pragma unroll
        for (int b = 0; b < 4; b++) {
            int o = k * 16 + a * 4 + b;
            float s = pb[o];
#pragma unroll
            for (int c = 0; c < 8; c++)
#pragma unroll
                for (int i = 0; i < 4; i++)
                    s += pw[o * 32 + c * 4 + i] * rps[c * 32 + t * 4 + i];
            v[b] = s;
        }
        float mx = fmaxf(fmaxf(v[0], v[1]), fmaxf(v[2], v[3]));
        float e[4]; float sum = 0.f;
#pragma unroll
        for (int b = 0; b < 4; b++) { e[b] = expf(v[b] - mx); sum += e[b]; }
        float inv = 1.f / sum;
        int base = ((nn * 8 + k) * 8 + t) * 16 + a * 4;
#pragma unroll
        for (int b = 0; b < 4; b++) P[base + b] = e[b] * inv;
    }
    {   // q: tid = k*32 + b*8 + t; softmax over a
        int k = tid >> 5, b = (tid >> 3) & 3, t = tid & 7;
        float v[4];
#pragma unroll
        for (int a = 0; a < 4; a++) {
            int o = k * 16 + a * 4 + b;
            float s = qb[o];
#pragma unroll
            for (int c = 0; c < 8; c++)
#pragma unroll
                for (int i = 0; i < 4; i++)
                    s += qw[o * 32 + c * 4 + i] * cps[c * 32 + t * 4 + i];
            v[a] = s;
        }
        float mx = fmaxf(fmaxf(v[0], v[1]), fmaxf(v[2], v[3]));
        float e[4]; float sum = 0.f;
#pragma unroll
        for (int a = 0; a < 4; a++) { e[a] = expf(v[a] - mx); sum += e[a]; }
        float inv = 1.f / sum;
        int base = ((nn * 8 + k) * 8 + t) * 16 + b;
#pragma unroll
        for (int a = 0; a < 4; a++) Q[base + a * 4] = e[a] * inv;
    }
    if (tid < 16) {  // tm
        int kk = tid >> 1, a2 = tid & 1;
        float v[2];
#pragma unroll
        for (int b2 = 0; b2 < 2; b2++) {
            int o = kk * 4 + a2 * 2 + b2;
            float s = tbv[o];
#pragma unroll
            for (int c = 0; c < 8; c++)
#pragma unroll
                for (int i = 0; i < 2; i++)
                    s += tw[o * 16 + c * 2 + i] * tpss[c * 2 + i];
            v[b2] = s;
        }
        float mx = fmaxf(v[0], v[1]);
        float e0 = expf(v[0] - mx), e1 = expf(v[1] - mx);
        float inv = 1.f / (e0 + e1);
        TM[nn * 32 + kk * 4 + a2 * 2 + 0] = e0 * inv;
        TM[nn * 32 + kk * 4 + a2 * 2 + 1] = e1 * inv;
    }
}

// ---------------------------------------------------------------------------
// K3a: block-linear mixing, TRANSPOSED output y3T[n][p][c] (bf16, k-major).
// grid (u2*8+u = 32, cg = 8, n = 8), 256 threads.
// Block covers t in {u2,u2+4}, h in {u,u+8,u+16,u+24}, all w, c in 64-chunk.
// x-tile staged in LDS with XOR-swizzled 16B chunks (conflict-free c-strided
// reads); mix in registers; transpose via 32KB LDS out-tile; 128B row writes.
// ---------------------------------------------------------------------------
__global__ __launch_bounds__(256) void k_mix(
    const float* __restrict__ x, const float* __restrict__ P,
    const float* __restrict__ Q, const float* __restrict__ TM,
    unsigned short* __restrict__ y3T)
{
    const int u2  = blockIdx.x >> 3;   // 0..3 (t-pair)
    const int u   = blockIdx.x & 7;    // 0..7 (row-within-block)
    const int cg  = blockIdx.y;        // 0..7 (64-channel group = kc = kk)
    const int nn  = blockIdx.z;        // 0..7
    const int tid = threadIdx.x;       // 0..255

    __shared__ float xs[16384];            // 64 KB: 512 rows x 32 w, swizzled
    __shared__ unsigned short ys[16384];   // 32 KB: [tt][a][w][c]

    // ---- load x tile: 512 rows (tt,b,c) x 128 B, swizzled chunk layout ----
    const size_t xbase = (size_t)nn * 512 * 8192 + (size_t)cg * 64 * 8192;
#pragma unroll
    for (int rr = 0; rr < 16; rr++) {
        int id  = rr * 256 + tid;          // LDS chunk position
        int row = id >> 3;                 // (tt*4+b)*64 + c
        int jw  = (id & 7) ^ (row & 7);    // swizzle: global w-chunk
        int tt = row >> 8, b = (row >> 6) & 3, c = row & 63;
        const float* src = x + xbase + (size_t)c * 8192
                             + (u2 + 4 * tt) * 1024 + (b * 8 + u) * 32 + jw * 4;
        *(float4*)&xs[id * 4] = *(const float4*)src;
    }

    // ---- per-thread mixing coefficients ----
    const int a = tid >> 6, c = tid & 63;
    float Pt[2][4], Qt[2][4][4];
#pragma unroll
    for (int tt = 0; tt < 2; tt++) {
        const float* Pb = &P[((nn * 8 + cg) * 8 + (u2 + 4 * tt)) * 16];
        const float* Qb = &Q[((nn * 8 + cg) * 8 + (u2 + 4 * tt)) * 16];
#pragma unroll
        for (int b = 0; b < 4; b++) Pt[tt][b] = Pb[a * 4 + b];
#pragma unroll
        for (int aw = 0; aw < 4; aw++)
#pragma unroll
            for (int bw = 0; bw < 4; bw++) Qt[tt][aw][bw] = Qb[aw * 4 + bw];
    }
    const float* TMb = &TM[nn * 32 + cg * 4];
    const float tm00 = TMb[0], tm01 = TMb[1], tm10 = TMb[2], tm11 = TMb[3];
    __syncthreads();

    // ---- h-mix into registers: y1[tt][w] for own (a, c) ----
    float y1[2][32];
#pragma unroll
    for (int tt = 0; tt < 2; tt++) {
#pragma unroll
        for (int w = 0; w < 32; w++) y1[tt][w] = 0.f;
#pragma unroll
        for (int b = 0; b < 4; b++) {
            int row = (tt * 4 + b) * 64 + c;
            float pv = Pt[tt][b];
#pragma unroll
            for (int jw = 0; jw < 8; jw++) {
                int chunk = row * 8 + (jw ^ (c & 7));
                float4 xv = *(const float4*)&xs[chunk * 4];
                y1[tt][jw * 4 + 0] += pv * xv.x;
                y1[tt][jw * 4 + 1] += pv * xv.y;
                y1[tt][jw * 4 + 2] += pv * xv.z;
                y1[tt][jw * 4 + 3] += pv * xv.w;
            }
        }
    }
    // ---- w-mix + t-mix on the fly, write ys[tt][a][w][c] ----
#pragma unroll
    for (int w = 0; w < 32; w++) {
        int bw = w >> 3, v = w & 7;
        float s0 = 0.f, s1 = 0.f;
#pragma unroll
        for (int aw = 0; aw < 4; aw++) {
            s0 += Qt[0][aw][bw] * y1[0][aw * 8 + v];
            s1 += Qt[1][aw][bw] * y1[1][aw * 8 + v];
        }
        ys[((0 + a) * 32 + w) * 64 + c] = f2bf(tm00 * s0 + tm01 * s1);
        ys[((4 + a) * 32 + w) * 64 + c] = f2bf(tm10 * s0 + tm11 * s1);
    }
    __syncthreads();

    // ---- write out: 256 rows (tt,a,w) x 128 B to y3T[p][cg*64..] ----
#pragma unroll
    for (int it = 0; it < 8; it++) {
        int id  = it * 256 + tid;
        int row = id >> 3, jc = id & 7;    // row = (tt*4+a)*32 + w
        int tt = row >> 7, aa = (row >> 5) & 3, w = row & 31;
        int p = (u2 + 4 * tt) * 1024 + (aa * 8 + u) * 32 + w;
        uint4 val = *(const uint4*)&ys[id * 8];
        *(uint4*)&y3T[((size_t)nn * 8192 + p) * 512 + cg * 64 + jc * 8] = val;
    }
}

// ---------------------------------------------------------------------------
// K3b: conv2 + BN2 + ReLU, bf16 MFMA GEMM. Both A (w2bf) and B (y3T) are
// k-major: staged via global_load_lds w16 with XOR chunk swizzle
// (pos = row*8 + (j ^ (row&7))) so frag ds_read_b128 hits all 8 bank-quads
// uniformly. Block 128co x 128p, BK=64, 4 waves x (4x4) 16x16x32 frags.
// ---------------------------------------------------------------------------
__global__ __launch_bounds__(256) void k_gemm2(
    const unsigned short* __restrict__ y3T,
    const unsigned short* __restrict__ w2bf,
    const float* __restrict__ b2, const float* __restrict__ g2,
    const float* __restrict__ bb2,const float* __restrict__ m2,
    const float* __restrict__ v2, float* __restrict__ out)
{
    const int ct  = blockIdx.x;   // 0..3  co-tile (inner: shares y3T tile)
    const int pt  = blockIdx.y;   // 0..63 p-tile
    const int nn  = blockIdx.z;   // 0..7
    const int tid = threadIdx.x;
    const int co0 = ct * 128, p0 = pt * 128;

    __shared__ unsigned short As[8192];  // 16 KB swizzled [co][c]
    __shared__ unsigned short Bs[8192];  // 16 KB swizzled [p][c]
    __shared__ float sc_s[128], ba_s[128];

    if (tid < 128) {
        int co = co0 + tid;
        float sc = g2[co] * rsqrtf(v2[co] + EPS);
        sc_s[tid] = sc;
        ba_s[tid] = (b2[co] - m2[co]) * sc + bb2[co];
    }

    const int lane = tid & 63, wv = tid >> 6;
    const int wr = wv >> 1, wc = wv & 1;
    const int ln15 = lane & 15, quad = lane >> 4;

    // DMA lane decode: row-in-group + swizzled c-chunk
    const int lrow = lane >> 3;
    const int jc   = (lane & 7) ^ lrow;

    f32x4 acc[4][4];
#pragma unroll
    for (int i = 0; i < 4; i++)
#pragma unroll
        for (int j = 0; j < 4; j++) acc[i][j] = (f32x4){0.f, 0.f, 0.f, 0.f};

    const unsigned short* Ag = w2bf + (size_t)co0 * 512;
    const unsigned short* Bg = y3T + ((size_t)nn * 8192 + p0) * 512;

    for (int c0 = 0; c0 < 512; c0 += 64) {
#pragma unroll
        for (int it = 0; it < 4; it++) {
            int rb = (wv * 4 + it) * 8;
            load_lds16(Ag + (size_t)(rb + lrow) * 512 + c0 + jc * 8,
                       &As[(wv * 4 + it) * 512]);
            load_lds16(Bg + (size_t)(rb + lrow) * 512 + c0 + jc * 8,
                       &Bs[(wv * 4 + it) * 512]);
        }
        __syncthreads();

#pragma unroll
        for (int ks = 0; ks < 2; ks++) {
            bf16x8 a[4], b[4];
#pragma unroll
            for (int mi = 0; mi < 4; mi++) {
                int row = wr * 64 + mi * 16 + ln15;
                int chunk = row * 8 + ((ks * 4 + quad) ^ (row & 7));
                a[mi] = *(const bf16x8*)&As[chunk * 8];
            }
#pragma unroll
            for (int pi = 0; pi < 4; pi++) {
                int row = wc * 64 + pi * 16 + ln15;
                int chunk = row * 8 + ((ks * 4 + quad) ^ (row & 7));
                b[pi] = *(const bf16x8*)&Bs[chunk * 8];
            }
#pragma unroll
            for (int mi = 0; mi < 4; mi++)
#pragma unroll
                for (int pi = 0; pi < 4; pi++)
                    acc[mi][pi] = __builtin_amdgcn_mfma_f32_16x16x32_bf16(
                        a[mi], b[pi], acc[mi][pi], 0, 0, 0);
        }
        __syncthreads();
    }

    // epilogue: BN2 + ReLU. D layout: col(p)=lane&15, row(co)=quad*4+reg.
#pragma unroll
    for (int mi = 0; mi < 4; mi++) {
        int lco = wr * 64 + mi * 16 + quad * 4;
#pragma unroll
        for (int pi = 0; pi < 4; pi++) {
            int p = p0 + wc * 64 + pi * 16 + ln15;
#pragma unroll
            for (int r = 0; r < 4; r++) {
                float vv = acc[mi][pi][r] * sc_s[lco + r] + ba_s[lco + r];
                out[((size_t)nn * 512 + co0 + lco + r) * 8192 + p] =
                    fmaxf(vv, 0.f);
            }
        }
    }
}

// ---------------------------------------------------------------------------
extern "C" void kernel_launch(void* const* d_in, const int* in_sizes, int n_in,
                              void* d_out, int out_size, void* d_ws, size_t ws_size,
                              hipStream_t stream) {
    const float* x   = (const float*)d_in[0];
    const float* w1  = (const float*)d_in[1];
    const float* b1  = (const float*)d_in[2];
    const float* g1  = (const float*)d_in[3];
    const float* bb1 = (const float*)d_in[4];
    const float* m1  = (const float*)d_in[5];
    const float* v1  = (const float*)d_in[6];
    const float* pw  = (const float*)d_in[7];
    const float* pb  = (const float*)d_in[8];
    const float* qw  = (const float*)d_in[9];
    const float* qb  = (const float*)d_in[10];
    const float* tw  = (const float*)d_in[11];
    const float* tbv = (const float*)d_in[12];
    const float* w2  = (const float*)d_in[13];
    const float* b2  = (const float*)d_in[14];
    const float* g2  = (const float*)d_in[15];
    const float* bb2 = (const float*)d_in[16];
    const float* m2  = (const float*)d_in[17];
    const float* v2  = (const float*)d_in[18];

    float* ws  = (float*)d_ws;
    float* rp  = ws;            // 2048 floats
    float* cp  = ws + 2048;     // 2048
    float* tps = ws + 4096;     // 128
    float* P   = ws + 8192;     // 8192
    float* Q   = ws + 16384;    // 8192
    float* TM  = ws + 24576;    // 256
    unsigned short* w2bf = (unsigned short*)(ws + 32768);   // 262144 ushorts
    unsigned short* y3T  = (unsigned short*)(ws + 163840);  // 33554432 ushorts

    // zero the atomic-reduction region (ws is poisoned 0xAA by harness)
    hipMemsetAsync(ws, 0, 4224 * sizeof(float), stream);

    k_w2cast<<<dim3(256), 256, 0, stream>>>(w2, w2bf);
    k_conv1_pool<<<dim3(4, 8, 8), 512, 0, stream>>>(x, w1, b1, g1, bb1, m1, v1,
                                                    rp, cp, tps);
    k_pqtm<<<dim3(8), 256, 0, stream>>>(rp, cp, tps, pw, pb, qw, qb, tw, tbv,
                                        P, Q, TM);
    k_mix<<<dim3(32, 8, 8), 256, 0, stream>>>(x, P, Q, TM, y3T);
    k_gemm2<<<dim3(4, 64, 8), 256, 0, stream>>>(y3T, w2bf, b2, g2, bb2, m2, v2,
                                                (float*)d_out);
}

// Round 4
// 347.939 us; speedup vs baseline: 2.0494x; 1.0508x over previous
//
#include <hip/hip_runtime.h>
#include <math.h>

#define EPS 1e-5f
// dims: n=8, C=512, t=8, h=32, w=32, K=8, S=4 (hb=wb=8), TS=2 (tb=4), TK=8

typedef __bf16 bf16x8 __attribute__((ext_vector_type(8)));
typedef float f32x4 __attribute__((ext_vector_type(4)));

__device__ static inline unsigned short f2bf(float f) {
    unsigned u = __float_as_uint(f);
    unsigned r = (u + 0x7fffu + ((u >> 16) & 1u)) >> 16;  // RNE
    return (unsigned short)r;
}

__device__ static inline void load_lds16(const void* g, void* l) {
    __builtin_amdgcn_global_load_lds(
        (const __attribute__((address_space(1))) unsigned int*)g,
        (__attribute__((address_space(3))) unsigned int*)l, 16, 0, 0);
}

// ---------------------------------------------------------------------------
// K1: conv1(512->8)+BN1+ReLU on the fly; pools rp/cp/tp. Also folds the
// w2 fp32->bf16 cast into spare bandwidth (first 65536 global threads).
// grid (a=4, t=8, n=8), 512 threads = 8 waves. Wave wv owns channels
// [wv*64, wv*64+64) -> weights wave-uniform. Lane owns float4 of 4 positions.
// ---------------------------------------------------------------------------
__global__ __launch_bounds__(512) void k_conv1_pool(
    const float* __restrict__ x,  const float* __restrict__ w1,
    const float* __restrict__ b1, const float* __restrict__ g1,
    const float* __restrict__ bb1,const float* __restrict__ m1,
    const float* __restrict__ v1,
    const float* __restrict__ w2, unsigned short* __restrict__ w2bf,
    float* __restrict__ rp, float* __restrict__ cp, float* __restrict__ tps)
{
    const int a   = blockIdx.x;   // 0..3 (h-block)
    const int t   = blockIdx.y;   // 0..7
    const int nn  = blockIdx.z;   // 0..7
    const int tid = threadIdx.x;  // 0..511
    const int wv  = tid >> 6;     // wave = c-group
    const int lane= tid & 63;

    __shared__ float part[8 * 8 * 256];  // [wv][k][pos] 64 KB

    // folded w2 cast (1 MB read total across grid)
    {
        int gid = (((nn * 8 + t) * 4 + a) * 512) + tid;
        if (gid < 65536) {
            float4 v = *(const float4*)&w2[gid * 4];
            ushort4 o;
            o.x = f2bf(v.x); o.y = f2bf(v.y); o.z = f2bf(v.z); o.w = f2bf(v.w);
            *(ushort4*)&w2bf[gid * 4] = o;
        }
    }

    const int cbase = __builtin_amdgcn_readfirstlane(wv) * 64;
    const float* xb = x + (size_t)nn * 512 * 8192 + (size_t)cbase * 8192
                        + t * 1024 + a * 256 + lane * 4;
    const float* wb = w1 + cbase;

    f32x4 acc[8];
#pragma unroll
    for (int k = 0; k < 8; k++) acc[k] = (f32x4){0.f, 0.f, 0.f, 0.f};

    for (int c = 0; c < 64; c += 8) {
        float4 xv[8];
#pragma unroll
        for (int cc = 0; cc < 8; cc++)
            xv[cc] = *(const float4*)(xb + (size_t)(c + cc) * 8192);
#pragma unroll
        for (int cc = 0; cc < 8; cc++) {
#pragma unroll
            for (int k = 0; k < 8; k++) {
                float wt = wb[k * 512 + c + cc];  // wave-uniform -> s_load
                acc[k][0] += wt * xv[cc].x;
                acc[k][1] += wt * xv[cc].y;
                acc[k][2] += wt * xv[cc].z;
                acc[k][3] += wt * xv[cc].w;
            }
        }
    }
#pragma unroll
    for (int k = 0; k < 8; k++)
        *(f32x4*)&part[(wv * 8 + k) * 256 + lane * 4] = acc[k];
    __syncthreads();

    {
        const int k = tid >> 6;
        f32x4 s = (f32x4){0.f, 0.f, 0.f, 0.f};
#pragma unroll
        for (int g = 0; g < 8; g++) {
            f32x4 p = *(const f32x4*)&part[(g * 8 + k) * 256 + lane * 4];
            s[0] += p[0]; s[1] += p[1]; s[2] += p[2]; s[3] += p[3];
        }
        const float sc = g1[k] * rsqrtf(v1[k] + EPS);
        const float ba = (b1[k] - m1[k]) * sc + bb1[k];
        float o0 = fmaxf(s[0] * sc + ba, 0.f);
        float o1 = fmaxf(s[1] * sc + ba, 0.f);
        float o2 = fmaxf(s[2] * sc + ba, 0.f);
        float o3 = fmaxf(s[3] * sc + ba, 0.f);

        float m4 = fmaxf(fmaxf(o0, o1), fmaxf(o2, o3));
        float s4 = o0 + o1 + o2 + o3;

        float mr = m4;
#pragma unroll
        for (int m = 32; m >= 1; m >>= 1) mr = fmaxf(mr, __shfl_xor(mr, m, 64));
        if (lane == 0) rp[((nn * 8 + k) * 8 + t) * 4 + a] = mr;

        float mc = m4;
        mc = fmaxf(mc, __shfl_xor(mc, 1, 64));
        mc = fmaxf(mc, __shfl_xor(mc, 8, 64));
        mc = fmaxf(mc, __shfl_xor(mc, 16, 64));
        mc = fmaxf(mc, __shfl_xor(mc, 32, 64));
        if ((lane & 0x39) == 0)
            atomicMax((int*)&cp[((nn * 8 + k) * 8 + t) * 4 + (lane >> 1)],
                      __float_as_int(mc));

        float ss = s4;
#pragma unroll
        for (int m = 32; m >= 1; m >>= 1) ss += __shfl_xor(ss, m, 64);
        if (lane == 0) atomicAdd(&tps[(nn * 8 + k) * 2 + (t >> 2)], ss);
    }
}

// ---------------------------------------------------------------------------
// K2: conv_p/conv_q/conv_t + softmaxes -> P, Q, TM. grid (n=8), 256 threads.
// ---------------------------------------------------------------------------
__global__ __launch_bounds__(256) void k_pqtm(
    const float* __restrict__ rp, const float* __restrict__ cp,
    const float* __restrict__ tps,
    const float* __restrict__ pw, const float* __restrict__ pb,
    const float* __restrict__ qw, const float* __restrict__ qb,
    const float* __restrict__ tw, const float* __restrict__ tbv,
    float* __restrict__ P, float* __restrict__ Q, float* __restrict__ TM)
{
    const int nn  = blockIdx.x;
    const int tid = threadIdx.x;
    __shared__ float rps[256], cps[256], tpss[16];
    rps[tid] = rp[nn * 256 + tid];
    cps[tid] = cp[nn * 256 + tid];
    if (tid < 16) tpss[tid] = tps[nn * 16 + tid] * (1.0f / 4096.0f);
    __syncthreads();

    {   // p: tid = k*32 + a*8 + t; softmax over b
        int k = tid >> 5, a = (tid >> 3) & 3, t = tid & 7;
        float v[4];
#pragma unroll
        for (int b = 0; b < 4; b++) {
            int o = k * 16 + a * 4 + b;
            float s = pb[o];
#pragma unroll
            for (int c = 0; c < 8; c++)
#pragma unroll
                for (int i = 0; i < 4; i++)
                    s += pw[o * 32 + c * 4 + i] * rps[c * 32 + t * 4 + i];
            v[b] = s;
        }
        float mx = fmaxf(fmaxf(v[0], v[1]), fmaxf(v[2], v[3]));
        float e[4]; float sum = 0.f;
#pragma unroll
        for (int b = 0; b < 4; b++) { e[b] = expf(v[b] - mx); sum += e[b]; }
        float inv = 1.f / sum;
        int base = ((nn * 8 + k) * 8 + t) * 16 + a * 4;
#pragma unroll
        for (int b = 0; b < 4; b++) P[base + b] = e[b] * inv;
    }
    {   // q: tid = k*32 + b*8 + t; softmax over a
        int k = tid >> 5, b = (tid >> 3) & 3, t = tid & 7;
        float v[4];
#pragma unroll
        for (int a = 0; a < 4; a++) {
            int o = k * 16 + a * 4 + b;
            float s = qb[o];
#pragma unroll
            for (int c = 0; c < 8; c++)
#pragma unroll
                for (int i = 0; i < 4; i++)
                    s += qw[o * 32 + c * 4 + i] * cps[c * 32 + t * 4 + i];
            v[a] = s;
        }
        float mx = fmaxf(fmaxf(v[0], v[1]), fmaxf(v[2], v[3]));
        float e[4]; float sum = 0.f;
#pragma unroll
        for (int a = 0; a < 4; a++) { e[a] = expf(v[a] - mx); sum += e[a]; }
        float inv = 1.f / sum;
        int base = ((nn * 8 + k) * 8 + t) * 16 + b;
#pragma unroll
        for (int a = 0; a < 4; a++) Q[base + a * 4] = e[a] * inv;
    }
    if (tid < 16) {  // tm
        int kk = tid >> 1, a2 = tid & 1;
        float v[2];
#pragma unroll
        for (int b2 = 0; b2 < 2; b2++) {
            int o = kk * 4 + a2 * 2 + b2;
            float s = tbv[o];
#pragma unroll
            for (int c = 0; c < 8; c++)
#pragma unroll
                for (int i = 0; i < 2; i++)
                    s += tw[o * 16 + c * 2 + i] * tpss[c * 2 + i];
            v[b2] = s;
        }
        float mx = fmaxf(v[0], v[1]);
        float e0 = expf(v[0] - mx), e1 = expf(v[1] - mx);
        float inv = 1.f / (e0 + e1);
        TM[nn * 32 + kk * 4 + a2 * 2 + 0] = e0 * inv;
        TM[nn * 32 + kk * 4 + a2 * 2 + 1] = e1 * inv;
    }
}

// ---------------------------------------------------------------------------
// K3a: block-linear mixing -> y3T[n][p][c] (bf16, k-major).
// grid (u2*8+u = 32, cg32 = 16, n = 8) = 4096 blocks, 256 threads.
// Block: t in {u2,u2+4}, h in {u,u+8,u+16,u+24}, all w, 32-channel group.
// LDS 48 KB -> 3 blocks/CU (12 waves/CU, vs 4 in R3). Thread = (a, vh, c32),
// computes y1 for v-range of 4 -> 32 regs. XOR-swizzled 16B chunks keep all
// LDS phases at the conflict-free minimum.
// ---------------------------------------------------------------------------
__global__ __launch_bounds__(256) void k_mix(
    const float* __restrict__ x, const float* __restrict__ P,
    const float* __restrict__ Q, const float* __restrict__ TM,
    unsigned short* __restrict__ y3T)
{
    const int u2  = blockIdx.x >> 3;   // 0..3 (t-pair)
    const int u   = blockIdx.x & 7;    // 0..7 (row-within-h-block)
    const int cg  = blockIdx.y;        // 0..15 (32-channel group)
    const int nn  = blockIdx.z;        // 0..7
    const int tid = threadIdx.x;       // 0..255
    const int kc  = cg >> 1;           // 64-chan group index for P/Q/TM

    __shared__ float xs[8192];             // 32 KB: 256 rows x 32 w, swizzled
    __shared__ unsigned short ys[8192];    // 16 KB: [tt][a][w][c32]

    // ---- load x tile: 256 rows (tt,b,c32) x 128 B, swizzled chunks ----
    const size_t xbase = (size_t)nn * 512 * 8192 + (size_t)cg * 32 * 8192;
#pragma unroll
    for (int rr = 0; rr < 8; rr++) {
        int id  = rr * 256 + tid;
        int row = id >> 3;                 // (tt*4+b)*32 + c
        int jw  = (id & 7) ^ (row & 7);    // swizzled w-chunk
        int tt = row >> 7, b = (row >> 5) & 3, c = row & 31;
        const float* src = x + xbase + (size_t)c * 8192
                             + (u2 + 4 * tt) * 1024 + (b * 8 + u) * 32 + jw * 4;
        *(float4*)&xs[id * 4] = *(const float4*)src;
    }

    const int a = tid >> 6, vh = (tid >> 5) & 1, c = tid & 31;
    float Pt[2][4], Qt[2][4][4];
#pragma unroll
    for (int tt = 0; tt < 2; tt++) {
        const float* Pb = &P[((nn * 8 + kc) * 8 + (u2 + 4 * tt)) * 16];
        const float* Qb = &Q[((nn * 8 + kc) * 8 + (u2 + 4 * tt)) * 16];
#pragma unroll
        for (int b = 0; b < 4; b++) Pt[tt][b] = Pb[a * 4 + b];
#pragma unroll
        for (int aw = 0; aw < 4; aw++)
#pragma unroll
            for (int bw = 0; bw < 4; bw++) Qt[tt][aw][bw] = Qb[aw * 4 + bw];
    }
    const float* TMb = &TM[nn * 32 + kc * 4];
    const float tm00 = TMb[0], tm01 = TMb[1], tm10 = TMb[2], tm11 = TMb[3];
    __syncthreads();

    // ---- h-mix: y1[tt][aw][vi] for own (a, vh, c) ----
    float y1[2][4][4];
#pragma unroll
    for (int tt = 0; tt < 2; tt++)
#pragma unroll
        for (int aw = 0; aw < 4; aw++)
#pragma unroll
            for (int vi = 0; vi < 4; vi++) y1[tt][aw][vi] = 0.f;
#pragma unroll
    for (int tt = 0; tt < 2; tt++) {
#pragma unroll
        for (int b = 0; b < 4; b++) {
            float pv = Pt[tt][b];
            int row = (tt * 4 + b) * 32 + c;
#pragma unroll
            for (int aw = 0; aw < 4; aw++) {
                int slot = (aw * 2 + vh) ^ (c & 7);
                float4 xv = *(const float4*)&xs[(row * 8 + slot) * 4];
                y1[tt][aw][0] += pv * xv.x;
                y1[tt][aw][1] += pv * xv.y;
                y1[tt][aw][2] += pv * xv.z;
                y1[tt][aw][3] += pv * xv.w;
            }
        }
    }
    // ---- w-mix + t-mix, write ys[tt2][a][w][c32] ----
#pragma unroll
    for (int bw = 0; bw < 4; bw++) {
#pragma unroll
        for (int vi = 0; vi < 4; vi++) {
            float s0 = 0.f, s1 = 0.f;
#pragma unroll
            for (int aw = 0; aw < 4; aw++) {
                s0 += Qt[0][aw][bw] * y1[0][aw][vi];
                s1 += Qt[1][aw][bw] * y1[1][aw][vi];
            }
            int wout = bw * 8 + vh * 4 + vi;
            ys[((0 + a) * 32 + wout) * 32 + c] = f2bf(tm00 * s0 + tm01 * s1);
            ys[((4 + a) * 32 + wout) * 32 + c] = f2bf(tm10 * s0 + tm11 * s1);
        }
    }
    __syncthreads();

    // ---- write out: 256 rows (tt,a,w) x 64 B to y3T[p][cg*32..] ----
#pragma unroll
    for (int it = 0; it < 4; it++) {
        int id  = it * 256 + tid;
        int row = id >> 2, jc = id & 3;    // row = (tt*4+a)*32 + w
        int tt = row >> 7, aa = (row >> 5) & 3, w = row & 31;
        int p = (u2 + 4 * tt) * 1024 + (aa * 8 + u) * 32 + w;
        uint4 val = *(const uint4*)&ys[row * 32 + jc * 8];
        *(uint4*)&y3T[((size_t)nn * 8192 + p) * 512 + cg * 32 + jc * 8] = val;
    }
}

// ---------------------------------------------------------------------------
// K3b: conv2 + BN2 + ReLU, bf16 MFMA GEMM; A (w2bf) and B (y3T) both k-major,
// staged via global_load_lds w16 + XOR chunk swizzle. 128co x 128p, BK=64,
// 4 waves x (4x4) 16x16x32 frags. Nontemporal out stores (write-once 268 MB).
// ---------------------------------------------------------------------------
__global__ __launch_bounds__(256) void k_gemm2(
    const unsigned short* __restrict__ y3T,
    const unsigned short* __restrict__ w2bf,
    const float* __restrict__ b2, const float* __restrict__ g2,
    const float* __restrict__ bb2,const float* __restrict__ m2,
    const float* __restrict__ v2, float* __restrict__ out)
{
    const int ct  = blockIdx.x;   // 0..3  co-tile (inner: shares y3T tile)
    const int pt  = blockIdx.y;   // 0..63 p-tile
    const int nn  = blockIdx.z;   // 0..7
    const int tid = threadIdx.x;
    const int co0 = ct * 128, p0 = pt * 128;

    __shared__ unsigned short As[8192];  // 16 KB swizzled [co][c]
    __shared__ unsigned short Bs[8192];  // 16 KB swizzled [p][c]
    __shared__ float sc_s[128], ba_s[128];

    if (tid < 128) {
        int co = co0 + tid;
        float sc = g2[co] * rsqrtf(v2[co] + EPS);
        sc_s[tid] = sc;
        ba_s[tid] = (b2[co] - m2[co]) * sc + bb2[co];
    }

    const int lane = tid & 63, wv = tid >> 6;
    const int wr = wv >> 1, wc = wv & 1;
    const int ln15 = lane & 15, quad = lane >> 4;

    const int lrow = lane >> 3;
    const int jc   = (lane & 7) ^ lrow;

    f32x4 acc[4][4];
#pragma unroll
    for (int i = 0; i < 4; i++)
#pragma unroll
        for (int j = 0; j < 4; j++) acc[i][j] = (f32x4){0.f, 0.f, 0.f, 0.f};

    const unsigned short* Ag = w2bf + (size_t)co0 * 512;
    const unsigned short* Bg = y3T + ((size_t)nn * 8192 + p0) * 512;

    for (int c0 = 0; c0 < 512; c0 += 64) {
#pragma unroll
        for (int it = 0; it < 4; it++) {
            int rb = (wv * 4 + it) * 8;
            load_lds16(Ag + (size_t)(rb + lrow) * 512 + c0 + jc * 8,
                       &As[(wv * 4 + it) * 512]);
            load_lds16(Bg + (size_t)(rb + lrow) * 512 + c0 + jc * 8,
                       &Bs[(wv * 4 + it) * 512]);
        }
        __syncthreads();

#pragma unroll
        for (int ks = 0; ks < 2; ks++) {
            bf16x8 a[4], b[4];
#pragma unroll
            for (int mi = 0; mi < 4; mi++) {
                int row = wr * 64 + mi * 16 + ln15;
                int chunk = row * 8 + ((ks * 4 + quad) ^ (row & 7));
                a[mi] = *(const bf16x8*)&As[chunk * 8];
            }
#pragma unroll
            for (int pi = 0; pi < 4; pi++) {
                int row = wc * 64 + pi * 16 + ln15;
                int chunk = row * 8 + ((ks * 4 + quad) ^ (row & 7));
                b[pi] = *(const bf16x8*)&Bs[chunk * 8];
            }
#pragma unroll
            for (int mi = 0; mi < 4; mi++)
#pragma unroll
                for (int pi = 0; pi < 4; pi++)
                    acc[mi][pi] = __builtin_amdgcn_mfma_f32_16x16x32_bf16(
                        a[mi], b[pi], acc[mi][pi], 0, 0, 0);
        }
        __syncthreads();
    }

    // epilogue: BN2 + ReLU; nontemporal (write-once, keep LLC for y3T/x)
#pragma unroll
    for (int mi = 0; mi < 4; mi++) {
        int lco = wr * 64 + mi * 16 + quad * 4;
#pragma unroll
        for (int pi = 0; pi < 4; pi++) {
            int p = p0 + wc * 64 + pi * 16 + ln15;
#pragma unroll
            for (int r = 0; r < 4; r++) {
                float vv = fmaxf(acc[mi][pi][r] * sc_s[lco + r] + ba_s[lco + r],
                                 0.f);
                __builtin_nontemporal_store(
                    vv, &out[((size_t)nn * 512 + co0 + lco + r) * 8192 + p]);
            }
        }
    }
}

// ---------------------------------------------------------------------------
extern "C" void kernel_launch(void* const* d_in, const int* in_sizes, int n_in,
                              void* d_out, int out_size, void* d_ws, size_t ws_size,
                              hipStream_t stream) {
    const float* x   = (const float*)d_in[0];
    const float* w1  = (const float*)d_in[1];
    const float* b1  = (const float*)d_in[2];
    const float* g1  = (const float*)d_in[3];
    const float* bb1 = (const float*)d_in[4];
    const float* m1  = (const float*)d_in[5];
    const float* v1  = (const float*)d_in[6];
    const float* pw  = (const float*)d_in[7];
    const float* pb  = (const float*)d_in[8];
    const float* qw  = (const float*)d_in[9];
    const float* qb  = (const float*)d_in[10];
    const float* tw  = (const float*)d_in[11];
    const float* tbv = (const float*)d_in[12];
    const float* w2  = (const float*)d_in[13];
    const float* b2  = (const float*)d_in[14];
    const float* g2  = (const float*)d_in[15];
    const float* bb2 = (const float*)d_in[16];
    const float* m2  = (const float*)d_in[17];
    const float* v2  = (const float*)d_in[18];

    float* ws  = (float*)d_ws;
    float* rp  = ws;            // 2048 floats
    float* cp  = ws + 2048;     // 2048
    float* tps = ws + 4096;     // 128
    float* P   = ws + 8192;     // 8192
    float* Q   = ws + 16384;    // 8192
    float* TM  = ws + 24576;    // 256
    unsigned short* w2bf = (unsigned short*)(ws + 32768);   // 262144 ushorts
    unsigned short* y3T  = (unsigned short*)(ws + 163840);  // 33554432 ushorts

    // zero the atomic-reduction region (ws is poisoned 0xAA by harness)
    hipMemsetAsync(ws, 0, 4224 * sizeof(float), stream);

    k_conv1_pool<<<dim3(4, 8, 8), 512, 0, stream>>>(x, w1, b1, g1, bb1, m1, v1,
                                                    w2, w2bf, rp, cp, tps);
    k_pqtm<<<dim3(8), 256, 0, stream>>>(rp, cp, tps, pw, pb, qw, qb, tw, tbv,
                                        P, Q, TM);
    k_mix<<<dim3(32, 16, 8), 256, 0, stream>>>(x, P, Q, TM, y3T);
    k_gemm2<<<dim3(4, 64, 8), 256, 0, stream>>>(y3T, w2bf, b2, g2, bb2, m2, v2,
                                                (float*)d_out);
}